// Round 1
// baseline (1133.050 us; speedup 1.0000x reference)
//
#include <hip/hip_runtime.h>

// Social-STGCN forward: 2x GCN(improved) + 3x GCLSTM(K=3 Cheb, H=C=0) + linear.
// N=50000 nodes, E=800000 edges, D=64.
//
// Simplifications (exact, from H=C=0 per cell):
//   gh(g) = bh[g] (cheb of zeros is bias only); f gate unused; Cn = i*t.
// Cheb terms z1 = lhat(x), z2 = 2*lhat(z1) - x shared across gates.
// Aggregation = CSR gather (built per call in ws), wave(64 lanes)=64 feats per node.

#define WAVE 64

// ---------- CSR build ----------
__global__ void count_deg_kernel(const int* __restrict__ ei, int* __restrict__ deg, int E) {
  int e = blockIdx.x * blockDim.x + threadIdx.x;
  if (e < E) atomicAdd(&deg[ei[E + e]], 1);
}

__global__ void prefix_kernel(const int* __restrict__ deg, int* __restrict__ rowptr,
                              int* __restrict__ cursor, int n) {
  __shared__ int sums[256];
  int tid = threadIdx.x;
  int seg = (n + 255) >> 8;
  int lo = tid * seg, hi = min(lo + seg, n);
  int s = 0;
  for (int i = lo; i < hi; ++i) s += deg[i];
  sums[tid] = s;
  __syncthreads();
  if (tid == 0) {
    int run = 0;
    for (int i = 0; i < 256; ++i) { int v = sums[i]; sums[i] = run; run += v; }
  }
  __syncthreads();
  int run = sums[tid];
  for (int i = lo; i < hi; ++i) { rowptr[i] = run; cursor[i] = run; run += deg[i]; }
}

__global__ void fill_kernel(const int* __restrict__ ei, int* __restrict__ cursor,
                            int* __restrict__ csr_src, int E) {
  int e = blockIdx.x * blockDim.x + threadIdx.x;
  if (e < E) {
    int d = ei[E + e];
    int pos = atomicAdd(&cursor[d], 1);
    csr_src[pos] = ei[e];
  }
}

__global__ void dinv_kernel(const int* __restrict__ deg, float* __restrict__ dg,
                            float* __restrict__ dc, int n) {
  int i = blockIdx.x * blockDim.x + threadIdx.x;
  if (i < n) {
    int d = deg[i];
    dg[i] = rsqrtf((float)d + 2.f);                  // GCN improved: deg+2, always finite
    dc[i] = d > 0 ? rsqrtf((float)d) : 0.f;          // Cheb: safe dinv
  }
}

// ---------- dense row matmul: OUT[n][64] = X[n][KIN] @ W[KIN][64] ----------
template <int KIN>
__global__ __launch_bounds__(64) void rowmm_kernel(const float* __restrict__ X,
                                                   const float* __restrict__ W,
                                                   float* __restrict__ OUT, int n) {
  __shared__ float xt[16 * KIN];
  int tid = threadIdx.x;
  int n0 = blockIdx.x * 16;
  for (int idx = tid; idx < 16 * KIN; idx += 64) xt[idx] = X[(size_t)n0 * KIN + idx];
  __syncthreads();
  float acc[16];
#pragma unroll
  for (int t = 0; t < 16; ++t) acc[t] = 0.f;
  for (int k = 0; k < KIN; ++k) {
    float w = W[k * 64 + tid];
#pragma unroll
    for (int t = 0; t < 16; ++t) acc[t] += xt[t * KIN + k] * w;
  }
#pragma unroll
  for (int t = 0; t < 16; ++t) OUT[(size_t)(n0 + t) * 64 + tid] = acc[t];
}

// ---------- gather (one wave per dst node, lane = feature) ----------
// MODE 0: GCN  -> OUT = relu(dinv_t*acc + 2*dinv_t^2*IN[node] + AUX(bias))
// MODE 1: z1   -> OUT = -dinv_t*acc
// MODE 2: z2   -> OUT = -2*dinv_t*acc - AUX[node]   (AUX = X)
template <int MODE>
__global__ void gather_kernel(const int* __restrict__ rowptr, const int* __restrict__ deg,
                              const int* __restrict__ csr_src, const float* __restrict__ dinv,
                              const float* __restrict__ IN, const float* __restrict__ AUX,
                              float* __restrict__ OUT, int n) {
  int node = blockIdx.x * (blockDim.x >> 6) + (threadIdx.x >> 6);
  if (node >= n) return;
  int lane = threadIdx.x & 63;
  int beg = rowptr[node];
  int cnt = deg[node];
  float acc = 0.f;
  for (int p = beg; p < beg + cnt; ++p) {
    int s = csr_src[p];
    acc += dinv[s] * IN[(size_t)s * 64 + lane];
  }
  float dt = dinv[node];
  size_t o = (size_t)node * 64 + lane;
  if (MODE == 0) {
    float v = dt * acc + 2.f * dt * dt * IN[o] + AUX[lane];
    OUT[o] = fmaxf(v, 0.f);
  } else if (MODE == 1) {
    OUT[o] = -dt * acc;
  } else {
    OUT[o] = -2.f * dt * acc - AUX[o];
  }
}

// ---------- fused 3-gate matmul + LSTM combine ----------
// [X|z1|z2] (16 nodes x 192) @ Wc(192 x 192) + bias, then
// i=sig(Gi), t=tanh(Gt), Cn=i*t, o=sig(Go+wc2*Cn), H=o*tanh(Cn).
// Writes H in place over X is safe: block only touches its own 16 rows,
// and all X reads are staged to LDS before the final store.
__global__ __launch_bounds__(192) void gate_kernel(
    const float* __restrict__ X, const float* __restrict__ Z1, const float* __restrict__ Z2,
    const float* __restrict__ wx,   // [4][3][64][64]
    const float* __restrict__ bx, const float* __restrict__ bh, const float* __restrict__ bg,
    const float* __restrict__ wc,   // [3][64]
    float* __restrict__ H, int n) {
  __shared__ float xt[16][192];
  int tid = threadIdx.x;
  int n0 = blockIdx.x * 16;
  {
    int term = tid >> 6, kd = tid & 63;
    const float* src = (term == 0) ? X : (term == 1 ? Z1 : Z2);
    for (int t = 0; t < 16; ++t) xt[t][tid] = src[(size_t)(n0 + t) * 64 + kd];
  }
  __syncthreads();
  int gate = tid >> 6, d = tid & 63;
  int g_src = (gate == 0) ? 0 : (gate == 1 ? 2 : 3);   // i, c(t), o
  const float* Wg = wx + (size_t)g_src * 3 * 64 * 64;
  float bias = bx[g_src * 64 + d] + bh[g_src * 64 + d] + bg[g_src * 64 + d];
  float acc[16];
#pragma unroll
  for (int t = 0; t < 16; ++t) acc[t] = bias;
  for (int k = 0; k < 192; ++k) {
    float w = Wg[k * 64 + d];   // [term][kd][d] contiguous in d -> coalesced per wave
#pragma unroll
    for (int t = 0; t < 16; ++t) acc[t] += xt[t][k] * w;
  }
  __syncthreads();
#pragma unroll
  for (int t = 0; t < 16; ++t) xt[t][tid] = acc[t];
  __syncthreads();
  for (int idx = tid; idx < 16 * 64; idx += 192) {
    int t = idx >> 6, d2 = idx & 63;
    float gi = xt[t][d2], gt = xt[t][64 + d2], go = xt[t][128 + d2];
    float ig = 1.f / (1.f + expf(-gi));
    float tt = tanhf(gt);
    float Cn = ig * tt;
    float og = 1.f / (1.f + expf(-(go + wc[2 * 64 + d2] * Cn)));
    H[(size_t)(n0 + t) * 64 + d2] = og * tanhf(Cn);
  }
}

// ---------- final linear: out[n][3] = relu(H[n][64]) @ lin_w[64][3] + lin_b ----------
__global__ void linear_kernel(const float* __restrict__ Hf, const float* __restrict__ lw,
                              const float* __restrict__ lb, float* __restrict__ out, int n) {
  int node = blockIdx.x * (blockDim.x >> 6) + (threadIdx.x >> 6);
  if (node >= n) return;
  int lane = threadIdx.x & 63;
  float v = fmaxf(Hf[(size_t)node * 64 + lane], 0.f);
  float a0 = v * lw[lane * 3 + 0];
  float a1 = v * lw[lane * 3 + 1];
  float a2 = v * lw[lane * 3 + 2];
  for (int off = 32; off; off >>= 1) {
    a0 += __shfl_down(a0, off);
    a1 += __shfl_down(a1, off);
    a2 += __shfl_down(a2, off);
  }
  if (lane == 0) {
    out[(size_t)node * 3 + 0] = a0 + lb[0];
    out[(size_t)node * 3 + 1] = a1 + lb[1];
    out[(size_t)node * 3 + 2] = a2 + lb[2];
  }
}

extern "C" void kernel_launch(void* const* d_in, const int* in_sizes, int n_in,
                              void* d_out, int out_size, void* d_ws, size_t ws_size,
                              hipStream_t stream) {
  const float* x      = (const float*)d_in[0];
  const int*   ei     = (const int*)d_in[1];
  const float* w_gcn1 = (const float*)d_in[2];
  const float* b_gcn1 = (const float*)d_in[3];
  const float* w_gcn2 = (const float*)d_in[4];
  const float* b_gcn2 = (const float*)d_in[5];
  const float* wx[3]  = {(const float*)d_in[6],  (const float*)d_in[12], (const float*)d_in[18]};
  const float* bx[3]  = {(const float*)d_in[7],  (const float*)d_in[13], (const float*)d_in[19]};
  const float* bh[3]  = {(const float*)d_in[9],  (const float*)d_in[15], (const float*)d_in[21]};
  const float* wc[3]  = {(const float*)d_in[10], (const float*)d_in[16], (const float*)d_in[22]};
  const float* bg[3]  = {(const float*)d_in[11], (const float*)d_in[17], (const float*)d_in[23]};
  const float* lin_w  = (const float*)d_in[24];
  const float* lin_b  = (const float*)d_in[25];
  float* out = (float*)d_out;

  int N = in_sizes[0] / 16;
  int E = in_sizes[1] / 2;

  char* ws = (char*)d_ws;
  size_t off = 0;
  auto alloc = [&](size_t bytes) {
    void* p = ws + off;
    off = (off + bytes + 255) & ~(size_t)255;
    return p;
  };
  int* deg      = (int*)alloc((size_t)N * 4);
  int* rowptr   = (int*)alloc((size_t)N * 4);
  int* cursor   = (int*)alloc((size_t)N * 4);
  int* csr_src  = (int*)alloc((size_t)E * 4);
  float* dinv_g = (float*)alloc((size_t)N * 4);
  float* dinv_c = (float*)alloc((size_t)N * 4);
  float* bufA   = (float*)alloc((size_t)N * 64 * 4);
  float* bufB   = (float*)alloc((size_t)N * 64 * 4);
  float* bufC   = (float*)alloc((size_t)N * 64 * 4);
  (void)ws_size; (void)n_in; (void)out_size;

  const int tb = 256;
  hipMemsetAsync(deg, 0, (size_t)N * 4, stream);
  count_deg_kernel<<<(E + tb - 1) / tb, tb, 0, stream>>>(ei, deg, E);
  prefix_kernel<<<1, 256, 0, stream>>>(deg, rowptr, cursor, N);
  fill_kernel<<<(E + tb - 1) / tb, tb, 0, stream>>>(ei, cursor, csr_src, E);
  dinv_kernel<<<(N + tb - 1) / tb, tb, 0, stream>>>(deg, dinv_g, dinv_c, N);

  int nb16 = (N + 15) / 16;   // 3125 tile blocks
  int nbw  = (N + 3) / 4;     // 4 node-waves per 256-thread block

  // GCN1: h1 = relu(gcn(x))          (bufA = h1)
  rowmm_kernel<16><<<nb16, 64, 0, stream>>>(x, w_gcn1, bufB, N);
  gather_kernel<0><<<nbw, 256, 0, stream>>>(rowptr, deg, csr_src, dinv_g, bufB, b_gcn1, bufA, N);
  // GCN2: h2 = relu(gcn(h1))         (bufA = h2)
  rowmm_kernel<64><<<nb16, 64, 0, stream>>>(bufA, w_gcn2, bufB, N);
  gather_kernel<0><<<nbw, 256, 0, stream>>>(rowptr, deg, csr_src, dinv_g, bufB, b_gcn2, bufA, N);

  // 3x GCLSTM: bufA = X -> H (in place via gate_kernel)
  for (int l = 0; l < 3; ++l) {
    gather_kernel<1><<<nbw, 256, 0, stream>>>(rowptr, deg, csr_src, dinv_c, bufA, nullptr, bufB, N); // z1
    gather_kernel<2><<<nbw, 256, 0, stream>>>(rowptr, deg, csr_src, dinv_c, bufB, bufA, bufC, N);    // z2
    gate_kernel<<<nb16, 192, 0, stream>>>(bufA, bufB, bufC, wx[l], bx[l], bh[l], bg[l], wc[l], bufA, N);
  }

  linear_kernel<<<nbw, 256, 0, stream>>>(bufA, lin_w, lin_b, out, N);
}

// Round 2
// 721.309 us; speedup vs baseline: 1.5708x; 1.5708x over previous
//
#include <hip/hip_runtime.h>

// Social-STGCN forward: 2x GCN(improved) + 3x GCLSTM(K=3 Cheb, H=C=0) + linear.
// N=50000 nodes, E=800000 edges, D=64.
//
// Exact simplifications (H=C=0 per cell): gh(g)=bh[g]; f gate dead; Cn=i*t.
// Cheb terms z1=lhat(x), z2=2*lhat(z1)-x shared across gates.
// Aggregation = CSR gather; CSR built per call (parallel scan).

// ---------- CSR build ----------
__global__ void count_deg_kernel(const int* __restrict__ ei, int* __restrict__ deg, int E) {
  int e = blockIdx.x * blockDim.x + threadIdx.x;
  if (e < E) atomicAdd(&deg[ei[E + e]], 1);
}

// block sums of deg (256 elems per block)
__global__ void scan_block_sums(const int* __restrict__ deg, int* __restrict__ bsum, int n) {
  int tid = threadIdx.x;
  int i = blockIdx.x * 256 + tid;
  int v = (i < n) ? deg[i] : 0;
  for (int off = 32; off; off >>= 1) v += __shfl_down(v, off);
  __shared__ int ws[4];
  int lane = tid & 63, wid = tid >> 6;
  if (lane == 0) ws[wid] = v;
  __syncthreads();
  if (tid == 0) bsum[blockIdx.x] = ws[0] + ws[1] + ws[2] + ws[3];
}

// exclusive scan of block sums (nb <= 256), single block
__global__ void scan_bsum(int* __restrict__ bsum, int nb) {
  __shared__ int tmp[256];
  int tid = threadIdx.x;
  int v = (tid < nb) ? bsum[tid] : 0;
  tmp[tid] = v;
  __syncthreads();
  for (int off = 1; off < 256; off <<= 1) {
    int t = (tid >= off) ? tmp[tid - off] : 0;
    __syncthreads();
    tmp[tid] += t;
    __syncthreads();
  }
  if (tid < nb) bsum[tid] = tmp[tid] - v;  // exclusive
}

// per-block exclusive scan + add block offset; also fills cursor and both dinv arrays
__global__ void scan_final(const int* __restrict__ deg, const int* __restrict__ bsum,
                           int* __restrict__ rowptr, int* __restrict__ cursor,
                           float* __restrict__ dg, float* __restrict__ dc, int n) {
  __shared__ int tmp[256];
  int tid = threadIdx.x;
  int i = blockIdx.x * 256 + tid;
  int v = (i < n) ? deg[i] : 0;
  tmp[tid] = v;
  __syncthreads();
  for (int off = 1; off < 256; off <<= 1) {
    int t = (tid >= off) ? tmp[tid - off] : 0;
    __syncthreads();
    tmp[tid] += t;
    __syncthreads();
  }
  if (i < n) {
    int excl = tmp[tid] - v + bsum[blockIdx.x];
    rowptr[i] = excl;
    cursor[i] = excl;
    dg[i] = rsqrtf((float)v + 2.f);                   // GCN improved: deg+2
    dc[i] = (v > 0) ? rsqrtf((float)v) : 0.f;         // Cheb safe dinv
  }
}

__global__ void fill_kernel(const int* __restrict__ ei, int* __restrict__ cursor,
                            int* __restrict__ csr_src, int E) {
  int e = blockIdx.x * blockDim.x + threadIdx.x;
  if (e < E) {
    int d = ei[E + e];
    int pos = atomicAdd(&cursor[d], 1);
    csr_src[pos] = ei[e];
  }
}

// ---------- dense row matmul: OUT[n][64] = X[n][KIN] @ W[KIN][64] ----------
template <int KIN>
__global__ __launch_bounds__(64) void rowmm_kernel(const float* __restrict__ X,
                                                   const float* __restrict__ W,
                                                   float* __restrict__ OUT, int n) {
  __shared__ float xt[16 * KIN];
  int tid = threadIdx.x;
  int n0 = blockIdx.x * 16;
  for (int idx = tid; idx < 16 * KIN; idx += 64) xt[idx] = X[(size_t)n0 * KIN + idx];
  __syncthreads();
  float acc[16];
#pragma unroll
  for (int t = 0; t < 16; ++t) acc[t] = 0.f;
  for (int k = 0; k < KIN; ++k) {
    float w = W[k * 64 + tid];
#pragma unroll
    for (int t = 0; t < 16; ++t) acc[t] += xt[t * KIN + k] * w;
  }
#pragma unroll
  for (int t = 0; t < 16; ++t) OUT[(size_t)(n0 + t) * 64 + tid] = acc[t];
}

// ---------- gather v2: one wave per node, 4 edge-slots x 16 lanes (float4) ----------
// MODE 0: GCN  -> OUT = relu(dt*acc + 2*dt^2*IN[node] + bias)
// MODE 1: z1   -> OUT = -dt*acc
// MODE 2: z2   -> OUT = -2*dt*acc - AUX[node]
template <int MODE>
__global__ void gather_kernel(const int* __restrict__ rowptr, const int* __restrict__ deg,
                              const int* __restrict__ csr_src, const float* __restrict__ dinv,
                              const float* __restrict__ IN, const float* __restrict__ AUX,
                              float* __restrict__ OUT, int n) {
  int node = blockIdx.x * (blockDim.x >> 6) + (threadIdx.x >> 6);
  if (node >= n) return;
  int lane = threadIdx.x & 63;
  int eg = lane >> 4;   // edge slot 0..3
  int f4 = lane & 15;   // float4 chunk of the 64-feature row
  int beg = rowptr[node], end = rowptr[node] + deg[node];
  const float4* IN4 = (const float4*)IN;
  float ax = 0.f, ay = 0.f, az = 0.f, aw = 0.f;
  for (int p = beg + eg; p < end; p += 4) {
    int s = csr_src[p];
    float dv = dinv[s];
    float4 v = IN4[(size_t)s * 16 + f4];
    ax += dv * v.x; ay += dv * v.y; az += dv * v.z; aw += dv * v.w;
  }
  // reduce across the 4 edge slots (lanes differing in bits 4,5)
  ax += __shfl_xor(ax, 16); ay += __shfl_xor(ay, 16);
  az += __shfl_xor(az, 16); aw += __shfl_xor(aw, 16);
  ax += __shfl_xor(ax, 32); ay += __shfl_xor(ay, 32);
  az += __shfl_xor(az, 32); aw += __shfl_xor(aw, 32);
  if (eg == 0) {
    float dt = dinv[node];
    size_t o4 = (size_t)node * 16 + f4;
    float4 r;
    if (MODE == 0) {
      float4 self = IN4[o4];
      float4 b = ((const float4*)AUX)[f4];
      float c2 = 2.f * dt * dt;
      r.x = fmaxf(dt * ax + c2 * self.x + b.x, 0.f);
      r.y = fmaxf(dt * ay + c2 * self.y + b.y, 0.f);
      r.z = fmaxf(dt * az + c2 * self.z + b.z, 0.f);
      r.w = fmaxf(dt * aw + c2 * self.w + b.w, 0.f);
    } else if (MODE == 1) {
      r.x = -dt * ax; r.y = -dt * ay; r.z = -dt * az; r.w = -dt * aw;
    } else {
      float4 xx = ((const float4*)AUX)[o4];
      r.x = -2.f * dt * ax - xx.x; r.y = -2.f * dt * ay - xx.y;
      r.z = -2.f * dt * az - xx.z; r.w = -2.f * dt * aw - xx.w;
    }
    ((float4*)OUT)[o4] = r;
  }
}

// ---------- fused 3-gate matmul + LSTM combine (1 wave / 16 nodes, 3 gates in regs) ----
__global__ __launch_bounds__(64) void gate_kernel(
    const float* __restrict__ X, const float* __restrict__ Z1, const float* __restrict__ Z2,
    const float* __restrict__ wx,   // [4][3][64][64]
    const float* __restrict__ bx, const float* __restrict__ bh, const float* __restrict__ bg,
    const float* __restrict__ wc,   // [3][64]
    float* __restrict__ H, int n) {
  __shared__ float xt[16][192];
  int tid = threadIdx.x;  // = output feature d
  int n0 = blockIdx.x * 16;
  for (int idx = tid; idx < 1024; idx += 64) {
    int t = idx >> 6, kd = idx & 63;
    xt[t][kd]       = X [(size_t)(n0 + t) * 64 + kd];
    xt[t][64 + kd]  = Z1[(size_t)(n0 + t) * 64 + kd];
    xt[t][128 + kd] = Z2[(size_t)(n0 + t) * 64 + kd];
  }
  __syncthreads();
  // gates used: i(0), c(2), o(3)
  const float* W0 = wx + (size_t)0 * 3 * 4096;
  const float* W1 = wx + (size_t)2 * 3 * 4096;
  const float* W2 = wx + (size_t)3 * 3 * 4096;
  float b0 = bx[0 * 64 + tid] + bh[0 * 64 + tid] + bg[0 * 64 + tid];
  float b1 = bx[2 * 64 + tid] + bh[2 * 64 + tid] + bg[2 * 64 + tid];
  float b2 = bx[3 * 64 + tid] + bh[3 * 64 + tid] + bg[3 * 64 + tid];
  float acc0[16], acc1[16], acc2[16];
#pragma unroll
  for (int t = 0; t < 16; ++t) { acc0[t] = b0; acc1[t] = b1; acc2[t] = b2; }
  for (int k = 0; k < 192; k += 4) {
    float w0[4], w1[4], w2[4];
#pragma unroll
    for (int j = 0; j < 4; ++j) {
      w0[j] = W0[(k + j) * 64 + tid];
      w1[j] = W1[(k + j) * 64 + tid];
      w2[j] = W2[(k + j) * 64 + tid];
    }
#pragma unroll
    for (int t = 0; t < 16; ++t) {
      float4 xv = *(const float4*)&xt[t][k];
      acc0[t] += xv.x * w0[0] + xv.y * w0[1] + xv.z * w0[2] + xv.w * w0[3];
      acc1[t] += xv.x * w1[0] + xv.y * w1[1] + xv.z * w1[2] + xv.w * w1[3];
      acc2[t] += xv.x * w2[0] + xv.y * w2[1] + xv.z * w2[2] + xv.w * w2[3];
    }
  }
  float wcd = wc[2 * 64 + tid];
#pragma unroll
  for (int t = 0; t < 16; ++t) {
    float ig = 1.f / (1.f + expf(-acc0[t]));
    float tt = tanhf(acc1[t]);
    float Cn = ig * tt;
    float og = 1.f / (1.f + expf(-(acc2[t] + wcd * Cn)));
    H[(size_t)(n0 + t) * 64 + tid] = og * tanhf(Cn);
  }
}

// ---------- final linear: out[n][3] = relu(H[n][64]) @ lin_w[64][3] + lin_b ----------
__global__ void linear_kernel(const float* __restrict__ Hf, const float* __restrict__ lw,
                              const float* __restrict__ lb, float* __restrict__ out, int n) {
  int node = blockIdx.x * (blockDim.x >> 6) + (threadIdx.x >> 6);
  if (node >= n) return;
  int lane = threadIdx.x & 63;
  float v = fmaxf(Hf[(size_t)node * 64 + lane], 0.f);
  float a0 = v * lw[lane * 3 + 0];
  float a1 = v * lw[lane * 3 + 1];
  float a2 = v * lw[lane * 3 + 2];
  for (int off = 32; off; off >>= 1) {
    a0 += __shfl_down(a0, off);
    a1 += __shfl_down(a1, off);
    a2 += __shfl_down(a2, off);
  }
  if (lane == 0) {
    out[(size_t)node * 3 + 0] = a0 + lb[0];
    out[(size_t)node * 3 + 1] = a1 + lb[1];
    out[(size_t)node * 3 + 2] = a2 + lb[2];
  }
}

extern "C" void kernel_launch(void* const* d_in, const int* in_sizes, int n_in,
                              void* d_out, int out_size, void* d_ws, size_t ws_size,
                              hipStream_t stream) {
  const float* x      = (const float*)d_in[0];
  const int*   ei     = (const int*)d_in[1];
  const float* w_gcn1 = (const float*)d_in[2];
  const float* b_gcn1 = (const float*)d_in[3];
  const float* w_gcn2 = (const float*)d_in[4];
  const float* b_gcn2 = (const float*)d_in[5];
  const float* wx[3]  = {(const float*)d_in[6],  (const float*)d_in[12], (const float*)d_in[18]};
  const float* bx[3]  = {(const float*)d_in[7],  (const float*)d_in[13], (const float*)d_in[19]};
  const float* bh[3]  = {(const float*)d_in[9],  (const float*)d_in[15], (const float*)d_in[21]};
  const float* wc[3]  = {(const float*)d_in[10], (const float*)d_in[16], (const float*)d_in[22]};
  const float* bg[3]  = {(const float*)d_in[11], (const float*)d_in[17], (const float*)d_in[23]};
  const float* lin_w  = (const float*)d_in[24];
  const float* lin_b  = (const float*)d_in[25];
  float* out = (float*)d_out;

  int N = in_sizes[0] / 16;
  int E = in_sizes[1] / 2;
  int nsb = (N + 255) / 256;   // scan blocks (must be <= 256; 196 here)

  char* ws = (char*)d_ws;
  size_t off = 0;
  auto alloc = [&](size_t bytes) {
    void* p = ws + off;
    off = (off + bytes + 255) & ~(size_t)255;
    return p;
  };
  int* deg      = (int*)alloc((size_t)N * 4);
  int* rowptr   = (int*)alloc((size_t)N * 4);
  int* cursor   = (int*)alloc((size_t)N * 4);
  int* bsum     = (int*)alloc((size_t)nsb * 4);
  int* csr_src  = (int*)alloc((size_t)E * 4);
  float* dinv_g = (float*)alloc((size_t)N * 4);
  float* dinv_c = (float*)alloc((size_t)N * 4);
  float* bufA   = (float*)alloc((size_t)N * 64 * 4);
  float* bufB   = (float*)alloc((size_t)N * 64 * 4);
  float* bufC   = (float*)alloc((size_t)N * 64 * 4);
  (void)ws_size; (void)n_in; (void)out_size;

  const int tb = 256;
  hipMemsetAsync(deg, 0, (size_t)N * 4, stream);
  count_deg_kernel<<<(E + tb - 1) / tb, tb, 0, stream>>>(ei, deg, E);
  scan_block_sums<<<nsb, 256, 0, stream>>>(deg, bsum, N);
  scan_bsum<<<1, 256, 0, stream>>>(bsum, nsb);
  scan_final<<<nsb, 256, 0, stream>>>(deg, bsum, rowptr, cursor, dinv_g, dinv_c, N);
  fill_kernel<<<(E + tb - 1) / tb, tb, 0, stream>>>(ei, cursor, csr_src, E);

  int nb16 = (N + 15) / 16;   // 3125 tile blocks
  int nbw  = (N + 3) / 4;     // 4 node-waves per 256-thread block

  // GCN1: h1 = relu(gcn(x))          (bufA = h1)
  rowmm_kernel<16><<<nb16, 64, 0, stream>>>(x, w_gcn1, bufB, N);
  gather_kernel<0><<<nbw, 256, 0, stream>>>(rowptr, deg, csr_src, dinv_g, bufB, b_gcn1, bufA, N);
  // GCN2: h2 = relu(gcn(h1))         (bufA = h2)
  rowmm_kernel<64><<<nb16, 64, 0, stream>>>(bufA, w_gcn2, bufB, N);
  gather_kernel<0><<<nbw, 256, 0, stream>>>(rowptr, deg, csr_src, dinv_g, bufB, b_gcn2, bufA, N);

  // 3x GCLSTM: bufA = X -> H (in place via gate_kernel)
  for (int l = 0; l < 3; ++l) {
    gather_kernel<1><<<nbw, 256, 0, stream>>>(rowptr, deg, csr_src, dinv_c, bufA, nullptr, bufB, N); // z1
    gather_kernel<2><<<nbw, 256, 0, stream>>>(rowptr, deg, csr_src, dinv_c, bufB, bufA, bufC, N);    // z2
    gate_kernel<<<nb16, 64, 0, stream>>>(bufA, bufB, bufC, wx[l], bx[l], bh[l], bg[l], wc[l], bufA, N);
  }

  linear_kernel<<<nbw, 256, 0, stream>>>(bufA, lin_w, lin_b, out, N);
}

// Round 3
// 544.179 us; speedup vs baseline: 2.0821x; 1.3255x over previous
//
#include <hip/hip_runtime.h>

// Social-STGCN forward: 2x GCN(improved) + 3x GCLSTM(K=3 Cheb, H=C=0) + linear.
// N=50000 nodes, E=800000 edges, D=64.
//
// Exact simplifications (H=C=0 per cell): gh(g)=bh[g]; f gate dead; Cn=i*t.
// Cheb terms z1=lhat(x), z2=2*lhat(z1)-x shared across gates.
// Gate matmul [X|Z1|Z2](Nx192) @ W(192x192) runs on MFMA fp16 (no fp32 MFMA on CDNA4).

typedef _Float16 half8 __attribute__((ext_vector_type(8)));
typedef _Float16 half4v __attribute__((ext_vector_type(4)));
typedef float f32x4 __attribute__((ext_vector_type(4)));

// ---------- CSR build ----------
__global__ void count_deg_kernel(const int* __restrict__ ei, int* __restrict__ deg, int E) {
  int e = blockIdx.x * blockDim.x + threadIdx.x;
  if (e < E) atomicAdd(&deg[ei[E + e]], 1);
}

__global__ void scan_block_sums(const int* __restrict__ deg, int* __restrict__ bsum, int n) {
  int tid = threadIdx.x;
  int i = blockIdx.x * 256 + tid;
  int v = (i < n) ? deg[i] : 0;
  for (int off = 32; off; off >>= 1) v += __shfl_down(v, off);
  __shared__ int ws[4];
  int lane = tid & 63, wid = tid >> 6;
  if (lane == 0) ws[wid] = v;
  __syncthreads();
  if (tid == 0) bsum[blockIdx.x] = ws[0] + ws[1] + ws[2] + ws[3];
}

__global__ void scan_bsum(int* __restrict__ bsum, int nb) {
  __shared__ int tmp[256];
  int tid = threadIdx.x;
  int v = (tid < nb) ? bsum[tid] : 0;
  tmp[tid] = v;
  __syncthreads();
  for (int off = 1; off < 256; off <<= 1) {
    int t = (tid >= off) ? tmp[tid - off] : 0;
    __syncthreads();
    tmp[tid] += t;
    __syncthreads();
  }
  if (tid < nb) bsum[tid] = tmp[tid] - v;  // exclusive
}

__global__ void scan_final(const int* __restrict__ deg, const int* __restrict__ bsum,
                           int* __restrict__ rowptr, int* __restrict__ cursor,
                           float* __restrict__ dg, float* __restrict__ dc, int n) {
  __shared__ int tmp[256];
  int tid = threadIdx.x;
  int i = blockIdx.x * 256 + tid;
  int v = (i < n) ? deg[i] : 0;
  tmp[tid] = v;
  __syncthreads();
  for (int off = 1; off < 256; off <<= 1) {
    int t = (tid >= off) ? tmp[tid - off] : 0;
    __syncthreads();
    tmp[tid] += t;
    __syncthreads();
  }
  if (i < n) {
    int excl = tmp[tid] - v + bsum[blockIdx.x];
    rowptr[i] = excl;
    cursor[i] = excl;
    dg[i] = rsqrtf((float)v + 2.f);
    dc[i] = (v > 0) ? rsqrtf((float)v) : 0.f;
  }
}

__global__ void fill_kernel(const int* __restrict__ ei, int* __restrict__ cursor,
                            int* __restrict__ csr_src, int E) {
  int e = blockIdx.x * blockDim.x + threadIdx.x;
  if (e < E) {
    int d = ei[E + e];
    int pos = atomicAdd(&cursor[d], 1);
    csr_src[pos] = ei[e];
  }
}

// ---------- pack gate weights -> fp16 MFMA B-fragment layout ----------
// Wpk[l][g][kc][nt][lane][j]; g in {i,c,o} = src gates {0,2,3}; k = kc*32 + klo,
// klo = (lane>>4)*8 + j; n = nt*16 + (lane&15). Source wx: [4][3][64][64].
__global__ void pack_w_kernel(const float* __restrict__ wx0, const float* __restrict__ wx1,
                              const float* __restrict__ wx2, _Float16* __restrict__ Wpk) {
  int idx = blockIdx.x * 256 + threadIdx.x;
  if (idx >= 3 * 3 * 192 * 64) return;
  int l = idx / 36864;
  int r = idx % 36864;
  int g = r / 12288;
  int r2 = r % 12288;
  int k = r2 / 64;   // 0..191
  int n = r2 % 64;
  const float* wx = (l == 0) ? wx0 : (l == 1 ? wx1 : wx2);
  int gs = (g == 0) ? 0 : (g == 1 ? 2 : 3);
  int tau = k >> 6, kd = k & 63;
  float v = wx[(((size_t)gs * 3 + tau) * 64 + kd) * 64 + n];
  int kc = k >> 5, klo = k & 31;
  int lane = ((klo >> 3) << 4) | (n & 15);
  int j = klo & 7;
  int nt = n >> 4;
  size_t dst = ((((size_t)l * 3 + g) * 6 + kc) * 4 + nt) * 512 + (size_t)lane * 8 + j;
  Wpk[dst] = (_Float16)v;
}

// ---------- dense row matmul: OUT[n][64] = X[n][KIN] @ W[KIN][64] ----------
template <int KIN>
__global__ __launch_bounds__(64) void rowmm_kernel(const float* __restrict__ X,
                                                   const float* __restrict__ W,
                                                   float* __restrict__ OUT, int n) {
  __shared__ float xt[16 * KIN];
  int tid = threadIdx.x;
  int n0 = blockIdx.x * 16;
  for (int idx = tid; idx < 16 * KIN; idx += 64) xt[idx] = X[(size_t)n0 * KIN + idx];
  __syncthreads();
  float acc[16];
#pragma unroll
  for (int t = 0; t < 16; ++t) acc[t] = 0.f;
  for (int k = 0; k < KIN; ++k) {
    float w = W[k * 64 + tid];
#pragma unroll
    for (int t = 0; t < 16; ++t) acc[t] += xt[t * KIN + k] * w;
  }
#pragma unroll
  for (int t = 0; t < 16; ++t) OUT[(size_t)(n0 + t) * 64 + tid] = acc[t];
}

// ---------- gather: one wave per node, 4 edge-slots x 16 lanes (float4) ----------
template <int MODE>
__global__ void gather_kernel(const int* __restrict__ rowptr, const int* __restrict__ deg,
                              const int* __restrict__ csr_src, const float* __restrict__ dinv,
                              const float* __restrict__ IN, const float* __restrict__ AUX,
                              float* __restrict__ OUT, int n) {
  int node = blockIdx.x * (blockDim.x >> 6) + (threadIdx.x >> 6);
  if (node >= n) return;
  int lane = threadIdx.x & 63;
  int eg = lane >> 4;
  int f4 = lane & 15;
  int beg = rowptr[node], end = rowptr[node] + deg[node];
  const float4* IN4 = (const float4*)IN;
  float ax = 0.f, ay = 0.f, az = 0.f, aw = 0.f;
  for (int p = beg + eg; p < end; p += 4) {
    int s = csr_src[p];
    float dv = dinv[s];
    float4 v = IN4[(size_t)s * 16 + f4];
    ax += dv * v.x; ay += dv * v.y; az += dv * v.z; aw += dv * v.w;
  }
  ax += __shfl_xor(ax, 16); ay += __shfl_xor(ay, 16);
  az += __shfl_xor(az, 16); aw += __shfl_xor(aw, 16);
  ax += __shfl_xor(ax, 32); ay += __shfl_xor(ay, 32);
  az += __shfl_xor(az, 32); aw += __shfl_xor(aw, 32);
  if (eg == 0) {
    float dt = dinv[node];
    size_t o4 = (size_t)node * 16 + f4;
    float4 r;
    if (MODE == 0) {
      float4 self = IN4[o4];
      float4 b = ((const float4*)AUX)[f4];
      float c2 = 2.f * dt * dt;
      r.x = fmaxf(dt * ax + c2 * self.x + b.x, 0.f);
      r.y = fmaxf(dt * ay + c2 * self.y + b.y, 0.f);
      r.z = fmaxf(dt * az + c2 * self.z + b.z, 0.f);
      r.w = fmaxf(dt * aw + c2 * self.w + b.w, 0.f);
    } else if (MODE == 1) {
      r.x = -dt * ax; r.y = -dt * ay; r.z = -dt * az; r.w = -dt * aw;
    } else {
      float4 xx = ((const float4*)AUX)[o4];
      r.x = -2.f * dt * ax - xx.x; r.y = -2.f * dt * ay - xx.y;
      r.z = -2.f * dt * az - xx.z; r.w = -2.f * dt * aw - xx.w;
    }
    ((float4*)OUT)[o4] = r;
  }
}

// ---------- MFMA gate kernel: 64 nodes/block, 16 nodes/wave, 3 gates in acc ----------
// acc layout (16x16x32): D row m=(lane>>4)*4+r, col n=lane&15.
// A: row m=lane&15, k=(lane>>4)*8+j (contig).  B: k=(lane>>4)*8+j, n=lane&15.
__global__ __launch_bounds__(256) void gate_mfma_kernel(
    const float* __restrict__ X, const float* __restrict__ Z1, const float* __restrict__ Z2,
    const _Float16* __restrict__ Wl,  // packed [3][6][4][64][8] for this layer
    const float* __restrict__ bx, const float* __restrict__ bh, const float* __restrict__ bg,
    const float* __restrict__ wc, float* __restrict__ H, int n) {
  __shared__ _Float16 U[64 * 200];  // 64 rows x 192 (+8 pad) halves; stride 400 B
  int tid = threadIdx.x;
  int n0 = blockIdx.x * 64;
  // stage [X|Z1|Z2] rows -> fp16 LDS
  const float4* S4[3] = {(const float4*)X, (const float4*)Z1, (const float4*)Z2};
#pragma unroll
  for (int s = 0; s < 3; ++s) {
    const float4* src = S4[s];
#pragma unroll
    for (int it = 0; it < 4; ++it) {
      int idx = it * 256 + tid;          // 0..1023
      int row = idx >> 4, c4 = idx & 15;
      int grow = min(n0 + row, n - 1);
      float4 v = src[(size_t)grow * 16 + c4];
      half4v h;
      h.x = (_Float16)v.x; h.y = (_Float16)v.y; h.z = (_Float16)v.z; h.w = (_Float16)v.w;
      *(half4v*)&U[row * 200 + s * 64 + c4 * 4] = h;
    }
  }
  __syncthreads();

  int wid = tid >> 6, lane = tid & 63;
  int dbase = lane & 15;
  const _Float16* Ubase = &U[(wid * 16 + dbase) * 200 + ((lane >> 4) << 3)];
  const _Float16* Wlane = Wl + (size_t)lane * 8;

  f32x4 acc[3][4];
#pragma unroll
  for (int g = 0; g < 3; ++g) {
    int gs = (g == 0) ? 0 : (g == 1 ? 2 : 3);
#pragma unroll
    for (int nt = 0; nt < 4; ++nt) {
      int d = nt * 16 + dbase;
      float b = bx[gs * 64 + d] + bh[gs * 64 + d] + bg[gs * 64 + d];
      acc[g][nt] = (f32x4){b, b, b, b};
    }
  }
#pragma unroll
  for (int kc = 0; kc < 6; ++kc) {
    half8 a = *(const half8*)(Ubase + kc * 32);
#pragma unroll
    for (int g = 0; g < 3; ++g) {
#pragma unroll
      for (int nt = 0; nt < 4; ++nt) {
        half8 b = *(const half8*)(Wlane + (size_t)(((g * 6 + kc) * 4 + nt)) * 512);
        acc[g][nt] = __builtin_amdgcn_mfma_f32_16x16x32_f16(a, b, acc[g][nt], 0, 0, 0);
      }
    }
  }
  int mrow = n0 + wid * 16 + (((lane >> 4)) << 2);
#pragma unroll
  for (int nt = 0; nt < 4; ++nt) {
    int d = nt * 16 + dbase;
    float wcd = wc[128 + d];
#pragma unroll
    for (int r = 0; r < 4; ++r) {
      int node = mrow + r;
      if (node < n) {
        float ig = 1.f / (1.f + expf(-acc[0][nt][r]));
        float tt = tanhf(acc[1][nt][r]);
        float Cn = ig * tt;
        float og = 1.f / (1.f + expf(-(acc[2][nt][r] + wcd * Cn)));
        H[(size_t)node * 64 + d] = og * tanhf(Cn);
      }
    }
  }
}

// ---------- final linear: out[n][3] = relu(H[n][64]) @ lin_w[64][3] + lin_b ----------
__global__ void linear_kernel(const float* __restrict__ Hf, const float* __restrict__ lw,
                              const float* __restrict__ lb, float* __restrict__ out, int n) {
  int node = blockIdx.x * (blockDim.x >> 6) + (threadIdx.x >> 6);
  if (node >= n) return;
  int lane = threadIdx.x & 63;
  float v = fmaxf(Hf[(size_t)node * 64 + lane], 0.f);
  float a0 = v * lw[lane * 3 + 0];
  float a1 = v * lw[lane * 3 + 1];
  float a2 = v * lw[lane * 3 + 2];
  for (int off = 32; off; off >>= 1) {
    a0 += __shfl_down(a0, off);
    a1 += __shfl_down(a1, off);
    a2 += __shfl_down(a2, off);
  }
  if (lane == 0) {
    out[(size_t)node * 3 + 0] = a0 + lb[0];
    out[(size_t)node * 3 + 1] = a1 + lb[1];
    out[(size_t)node * 3 + 2] = a2 + lb[2];
  }
}

extern "C" void kernel_launch(void* const* d_in, const int* in_sizes, int n_in,
                              void* d_out, int out_size, void* d_ws, size_t ws_size,
                              hipStream_t stream) {
  const float* x      = (const float*)d_in[0];
  const int*   ei     = (const int*)d_in[1];
  const float* w_gcn1 = (const float*)d_in[2];
  const float* b_gcn1 = (const float*)d_in[3];
  const float* w_gcn2 = (const float*)d_in[4];
  const float* b_gcn2 = (const float*)d_in[5];
  const float* wx[3]  = {(const float*)d_in[6],  (const float*)d_in[12], (const float*)d_in[18]};
  const float* bx[3]  = {(const float*)d_in[7],  (const float*)d_in[13], (const float*)d_in[19]};
  const float* bh[3]  = {(const float*)d_in[9],  (const float*)d_in[15], (const float*)d_in[21]};
  const float* wc[3]  = {(const float*)d_in[10], (const float*)d_in[16], (const float*)d_in[22]};
  const float* bg[3]  = {(const float*)d_in[11], (const float*)d_in[17], (const float*)d_in[23]};
  const float* lin_w  = (const float*)d_in[24];
  const float* lin_b  = (const float*)d_in[25];
  float* out = (float*)d_out;

  int N = in_sizes[0] / 16;
  int E = in_sizes[1] / 2;
  int nsb = (N + 255) / 256;

  char* ws = (char*)d_ws;
  size_t off = 0;
  auto alloc = [&](size_t bytes) {
    void* p = ws + off;
    off = (off + bytes + 255) & ~(size_t)255;
    return p;
  };
  int* deg      = (int*)alloc((size_t)N * 4);
  int* rowptr   = (int*)alloc((size_t)N * 4);
  int* cursor   = (int*)alloc((size_t)N * 4);
  int* bsum     = (int*)alloc((size_t)nsb * 4);
  int* csr_src  = (int*)alloc((size_t)E * 4);
  float* dinv_g = (float*)alloc((size_t)N * 4);
  float* dinv_c = (float*)alloc((size_t)N * 4);
  _Float16* Wpk = (_Float16*)alloc((size_t)3 * 36864 * 2);
  float* bufA   = (float*)alloc((size_t)N * 64 * 4);
  float* bufB   = (float*)alloc((size_t)N * 64 * 4);
  float* bufC   = (float*)alloc((size_t)N * 64 * 4);
  (void)ws_size; (void)n_in; (void)out_size;

  const int tb = 256;
  hipMemsetAsync(deg, 0, (size_t)N * 4, stream);
  count_deg_kernel<<<(E + tb - 1) / tb, tb, 0, stream>>>(ei, deg, E);
  scan_block_sums<<<nsb, 256, 0, stream>>>(deg, bsum, N);
  scan_bsum<<<1, 256, 0, stream>>>(bsum, nsb);
  scan_final<<<nsb, 256, 0, stream>>>(deg, bsum, rowptr, cursor, dinv_g, dinv_c, N);
  fill_kernel<<<(E + tb - 1) / tb, tb, 0, stream>>>(ei, cursor, csr_src, E);
  pack_w_kernel<<<(110592 + 255) / 256, 256, 0, stream>>>(wx[0], wx[1], wx[2], Wpk);

  int nb16 = (N + 15) / 16;
  int nb64 = (N + 63) / 64;
  int nbw  = (N + 3) / 4;

  // GCN1 / GCN2
  rowmm_kernel<16><<<nb16, 64, 0, stream>>>(x, w_gcn1, bufB, N);
  gather_kernel<0><<<nbw, 256, 0, stream>>>(rowptr, deg, csr_src, dinv_g, bufB, b_gcn1, bufA, N);
  rowmm_kernel<64><<<nb16, 64, 0, stream>>>(bufA, w_gcn2, bufB, N);
  gather_kernel<0><<<nbw, 256, 0, stream>>>(rowptr, deg, csr_src, dinv_g, bufB, b_gcn2, bufA, N);

  // 3x GCLSTM: bufA = X -> H in place
  for (int l = 0; l < 3; ++l) {
    gather_kernel<1><<<nbw, 256, 0, stream>>>(rowptr, deg, csr_src, dinv_c, bufA, nullptr, bufB, N);
    gather_kernel<2><<<nbw, 256, 0, stream>>>(rowptr, deg, csr_src, dinv_c, bufB, bufA, bufC, N);
    gate_mfma_kernel<<<nb64, 256, 0, stream>>>(bufA, bufB, bufC, Wpk + (size_t)l * 36864,
                                               bx[l], bh[l], bg[l], wc[l], bufA, N);
  }

  linear_kernel<<<nbw, 256, 0, stream>>>(bufA, lin_w, lin_b, out, N);
}

// Round 4
// 425.935 us; speedup vs baseline: 2.6601x; 1.2776x over previous
//
#include <hip/hip_runtime.h>

// Social-STGCN forward: 2x GCN(improved) + 3x GCLSTM(K=3 Cheb, H=C=0) + linear.
// N=50000 nodes, E=800000 edges, D=64.
//
// Exact simplifications (H=C=0 per cell): gh(g)=bh[g]; f gate dead; Cn=i*t.
// Cheb terms z1=lhat(x), z2=2*lhat(z1)-x shared across gates.
// Gate matmul [X|Z1|Z2](Nx192) @ W(192x192) on MFMA fp16.
// All feature tables stored fp16 (128B/row) to halve gather traffic; fp32 accum.

typedef _Float16 half8 __attribute__((ext_vector_type(8)));
typedef float f32x4 __attribute__((ext_vector_type(4)));

// ---------- CSR build ----------
__global__ void count_deg_kernel(const int* __restrict__ ei, int* __restrict__ deg, int E) {
  int e = blockIdx.x * blockDim.x + threadIdx.x;
  if (e < E) atomicAdd(&deg[ei[E + e]], 1);
}

__global__ void scan_block_sums(const int* __restrict__ deg, int* __restrict__ bsum, int n) {
  int tid = threadIdx.x;
  int i = blockIdx.x * 256 + tid;
  int v = (i < n) ? deg[i] : 0;
  for (int off = 32; off; off >>= 1) v += __shfl_down(v, off);
  __shared__ int ws[4];
  int lane = tid & 63, wid = tid >> 6;
  if (lane == 0) ws[wid] = v;
  __syncthreads();
  if (tid == 0) bsum[blockIdx.x] = ws[0] + ws[1] + ws[2] + ws[3];
}

__global__ void scan_bsum(int* __restrict__ bsum, int nb) {
  __shared__ int tmp[256];
  int tid = threadIdx.x;
  int v = (tid < nb) ? bsum[tid] : 0;
  tmp[tid] = v;
  __syncthreads();
  for (int off = 1; off < 256; off <<= 1) {
    int t = (tid >= off) ? tmp[tid - off] : 0;
    __syncthreads();
    tmp[tid] += t;
    __syncthreads();
  }
  if (tid < nb) bsum[tid] = tmp[tid] - v;  // exclusive
}

__global__ void scan_final(const int* __restrict__ deg, const int* __restrict__ bsum,
                           int* __restrict__ rowptr, int* __restrict__ cursor,
                           float* __restrict__ dg, float* __restrict__ dc, int n) {
  __shared__ int tmp[256];
  int tid = threadIdx.x;
  int i = blockIdx.x * 256 + tid;
  int v = (i < n) ? deg[i] : 0;
  tmp[tid] = v;
  __syncthreads();
  for (int off = 1; off < 256; off <<= 1) {
    int t = (tid >= off) ? tmp[tid - off] : 0;
    __syncthreads();
    tmp[tid] += t;
    __syncthreads();
  }
  if (i < n) {
    int excl = tmp[tid] - v + bsum[blockIdx.x];
    rowptr[i] = excl;
    cursor[i] = excl;
    dg[i] = rsqrtf((float)v + 2.f);
    dc[i] = (v > 0) ? rsqrtf((float)v) : 0.f;
  }
}

__global__ void fill_kernel(const int* __restrict__ ei, int* __restrict__ cursor,
                            int* __restrict__ csr_src, int E) {
  int e = blockIdx.x * blockDim.x + threadIdx.x;
  if (e < E) {
    int d = ei[E + e];
    int pos = atomicAdd(&cursor[d], 1);
    csr_src[pos] = ei[e];
  }
}

// ---------- pack gate weights -> fp16 MFMA B-fragment layout ----------
// Wpk[l][g][kc][nt][lane][j]; g in {i,c,o} = src gates {0,2,3}; k = kc*32 + klo,
// klo = (lane>>4)*8 + j; n = nt*16 + (lane&15). Source wx: [4][3][64][64].
__global__ void pack_w_kernel(const float* __restrict__ wx0, const float* __restrict__ wx1,
                              const float* __restrict__ wx2, _Float16* __restrict__ Wpk) {
  int idx = blockIdx.x * 256 + threadIdx.x;
  if (idx >= 3 * 3 * 192 * 64) return;
  int l = idx / 36864;
  int r = idx % 36864;
  int g = r / 12288;
  int r2 = r % 12288;
  int k = r2 / 64;   // 0..191
  int n = r2 % 64;
  const float* wx = (l == 0) ? wx0 : (l == 1 ? wx1 : wx2);
  int gs = (g == 0) ? 0 : (g == 1 ? 2 : 3);
  int tau = k >> 6, kd = k & 63;
  float v = wx[(((size_t)gs * 3 + tau) * 64 + kd) * 64 + n];
  int kc = k >> 5, klo = k & 31;
  int lane = ((klo >> 3) << 4) | (n & 15);
  int j = klo & 7;
  int nt = n >> 4;
  size_t dst = ((((size_t)l * 3 + g) * 6 + kc) * 4 + nt) * 512 + (size_t)lane * 8 + j;
  Wpk[dst] = (_Float16)v;
}

// ---------- GCN1 row matmul: OUT[n][64] = X[n][16] @ W[16][64]  (fp32 in, fp16 out) ----
__global__ __launch_bounds__(64) void rowmm16_kernel(const float* __restrict__ X,
                                                     const float* __restrict__ W,
                                                     _Float16* __restrict__ OUT, int n) {
  __shared__ float xt[16 * 16];
  int tid = threadIdx.x;
  int n0 = blockIdx.x * 16;
  for (int idx = tid; idx < 256; idx += 64) xt[idx] = X[(size_t)n0 * 16 + idx];
  __syncthreads();
  float acc[16];
#pragma unroll
  for (int t = 0; t < 16; ++t) acc[t] = 0.f;
  for (int k = 0; k < 16; ++k) {
    float w = W[k * 64 + tid];
#pragma unroll
    for (int t = 0; t < 16; ++t) acc[t] += xt[t * 16 + k] * w;
  }
#pragma unroll
  for (int t = 0; t < 16; ++t) OUT[(size_t)(n0 + t) * 64 + tid] = (_Float16)acc[t];
}

// ---------- GCN2 row matmul: OUT[n][64] = X[n][64] @ W[64][64]  (fp16 in, fp16 out) ----
__global__ __launch_bounds__(64) void rowmm64_kernel(const _Float16* __restrict__ Xh,
                                                     const float* __restrict__ W,
                                                     _Float16* __restrict__ OUT, int n) {
  __shared__ float xt[16 * 64];
  int tid = threadIdx.x;
  int n0 = blockIdx.x * 16;
  const half8* X8 = (const half8*)Xh;   // 8 half8 per row
#pragma unroll
  for (int it = 0; it < 2; ++it) {
    int i8 = it * 64 + tid;             // 0..127 (16 rows x 8 chunks)
    half8 v = X8[(size_t)n0 * 8 + i8];
#pragma unroll
    for (int j = 0; j < 8; ++j) xt[i8 * 8 + j] = (float)v[j];
  }
  __syncthreads();
  float acc[16];
#pragma unroll
  for (int t = 0; t < 16; ++t) acc[t] = 0.f;
  for (int k = 0; k < 64; ++k) {
    float w = W[k * 64 + tid];
#pragma unroll
    for (int t = 0; t < 16; ++t) acc[t] += xt[t * 64 + k] * w;
  }
#pragma unroll
  for (int t = 0; t < 16; ++t) OUT[(size_t)(n0 + t) * 64 + tid] = (_Float16)acc[t];
}

// ---------- gather v3: one wave per node, 8 edge-slots x 8 half8-lanes ----------
// MODE 0: GCN  -> OUT = relu(dt*acc + 2*dt^2*IN[node] + bias(AUX,fp32))
// MODE 1: z1   -> OUT = -dt*acc
// MODE 2: z2   -> OUT = -2*dt*acc - AUX[node]  (AUX fp16 table)
template <int MODE>
__global__ void gather_kernel(const int* __restrict__ rowptr, const int* __restrict__ deg,
                              const int* __restrict__ csr_src, const float* __restrict__ dinv,
                              const _Float16* __restrict__ IN, const void* __restrict__ AUX,
                              _Float16* __restrict__ OUT, int n) {
  int node = blockIdx.x * (blockDim.x >> 6) + (threadIdx.x >> 6);
  if (node >= n) return;
  int lane = threadIdx.x & 63;
  int eg = lane >> 3;   // edge slot 0..7
  int c8 = lane & 7;    // half8 chunk of the 64-feature row
  int beg = rowptr[node], end = rowptr[node] + deg[node];
  const half8* IN8 = (const half8*)IN;
  float acc[8];
#pragma unroll
  for (int j = 0; j < 8; ++j) acc[j] = 0.f;
  for (int p = beg + eg; p < end; p += 8) {
    int s = csr_src[p];
    float dv = dinv[s];
    half8 v = IN8[(size_t)s * 8 + c8];
#pragma unroll
    for (int j = 0; j < 8; ++j) acc[j] += dv * (float)v[j];
  }
  // reduce across the 8 edge slots (lane bits 3,4,5)
#pragma unroll
  for (int j = 0; j < 8; ++j) {
    acc[j] += __shfl_xor(acc[j], 8);
    acc[j] += __shfl_xor(acc[j], 16);
    acc[j] += __shfl_xor(acc[j], 32);
  }
  if (eg == 0) {
    float dt = dinv[node];
    size_t o8 = (size_t)node * 8 + c8;
    half8 r;
    if (MODE == 0) {
      half8 self = IN8[o8];
      const float* b = (const float*)AUX;
      float c2 = 2.f * dt * dt;
#pragma unroll
      for (int j = 0; j < 8; ++j) {
        float v = dt * acc[j] + c2 * (float)self[j] + b[c8 * 8 + j];
        r[j] = (_Float16)fmaxf(v, 0.f);
      }
    } else if (MODE == 1) {
#pragma unroll
      for (int j = 0; j < 8; ++j) r[j] = (_Float16)(-dt * acc[j]);
    } else {
      half8 xx = ((const half8*)AUX)[o8];
#pragma unroll
      for (int j = 0; j < 8; ++j) r[j] = (_Float16)(-2.f * dt * acc[j] - (float)xx[j]);
    }
    ((half8*)OUT)[o8] = r;
  }
}

// ---------- MFMA gate kernel: 64 nodes/block, 16 nodes/wave, no LDS ----------
// A frag loaded direct from fp16 tables: row m=lane&15, k=(lane>>4)*8+j.
// D: col n=lane&15, row m=(lane>>4)*4+r.
__global__ __launch_bounds__(256) void gate_mfma_kernel(
    const _Float16* __restrict__ X, const _Float16* __restrict__ Z1,
    const _Float16* __restrict__ Z2,
    const _Float16* __restrict__ Wl,  // packed [3][6][4][64][8] for this layer
    const float* __restrict__ bx, const float* __restrict__ bh, const float* __restrict__ bg,
    const float* __restrict__ wc, _Float16* __restrict__ H, int n) {
  int tid = threadIdx.x;
  int wid = tid >> 6, lane = tid & 63;
  int n0 = blockIdx.x * 64;
  int row = n0 + wid * 16 + (lane & 15);
  int rowc = min(row, n - 1);               // clamped load row (stores are guarded)
  int ksub = (lane >> 4) << 3;              // 0,8,16,24
  const _Float16* Wlane = Wl + (size_t)lane * 8;

  f32x4 acc[3][4];
  int dbase = lane & 15;
#pragma unroll
  for (int g = 0; g < 3; ++g) {
    int gs = (g == 0) ? 0 : (g == 1 ? 2 : 3);
#pragma unroll
    for (int nt = 0; nt < 4; ++nt) {
      int d = nt * 16 + dbase;
      float b = bx[gs * 64 + d] + bh[gs * 64 + d] + bg[gs * 64 + d];
      acc[g][nt] = (f32x4){b, b, b, b};
    }
  }
  const _Float16* T[3] = {X, Z1, Z2};
#pragma unroll
  for (int kc = 0; kc < 6; ++kc) {
    const _Float16* t = T[kc >> 1];
    half8 a = *(const half8*)&t[(size_t)rowc * 64 + ((kc & 1) << 5) + ksub];
#pragma unroll
    for (int g = 0; g < 3; ++g) {
#pragma unroll
      for (int nt = 0; nt < 4; ++nt) {
        half8 b = *(const half8*)(Wlane + (size_t)((g * 6 + kc) * 4 + nt) * 512);
        acc[g][nt] = __builtin_amdgcn_mfma_f32_16x16x32_f16(a, b, acc[g][nt], 0, 0, 0);
      }
    }
  }
  int mrow = n0 + wid * 16 + ((lane >> 4) << 2);
#pragma unroll
  for (int nt = 0; nt < 4; ++nt) {
    int d = nt * 16 + dbase;
    float wcd = wc[128 + d];
#pragma unroll
    for (int r = 0; r < 4; ++r) {
      int node = mrow + r;
      if (node < n) {
        float ig = 1.f / (1.f + expf(-acc[0][nt][r]));
        float tt = tanhf(acc[1][nt][r]);
        float Cn = ig * tt;
        float og = 1.f / (1.f + expf(-(acc[2][nt][r] + wcd * Cn)));
        H[(size_t)node * 64 + d] = (_Float16)(og * tanhf(Cn));
      }
    }
  }
}

// ---------- final linear: out[n][3] = relu(H[n][64]) @ lin_w[64][3] + lin_b ----------
__global__ void linear_kernel(const _Float16* __restrict__ Hf, const float* __restrict__ lw,
                              const float* __restrict__ lb, float* __restrict__ out, int n) {
  int node = blockIdx.x * (blockDim.x >> 6) + (threadIdx.x >> 6);
  if (node >= n) return;
  int lane = threadIdx.x & 63;
  float v = fmaxf((float)Hf[(size_t)node * 64 + lane], 0.f);
  float a0 = v * lw[lane * 3 + 0];
  float a1 = v * lw[lane * 3 + 1];
  float a2 = v * lw[lane * 3 + 2];
  for (int off = 32; off; off >>= 1) {
    a0 += __shfl_down(a0, off);
    a1 += __shfl_down(a1, off);
    a2 += __shfl_down(a2, off);
  }
  if (lane == 0) {
    out[(size_t)node * 3 + 0] = a0 + lb[0];
    out[(size_t)node * 3 + 1] = a1 + lb[1];
    out[(size_t)node * 3 + 2] = a2 + lb[2];
  }
}

extern "C" void kernel_launch(void* const* d_in, const int* in_sizes, int n_in,
                              void* d_out, int out_size, void* d_ws, size_t ws_size,
                              hipStream_t stream) {
  const float* x      = (const float*)d_in[0];
  const int*   ei     = (const int*)d_in[1];
  const float* w_gcn1 = (const float*)d_in[2];
  const float* b_gcn1 = (const float*)d_in[3];
  const float* w_gcn2 = (const float*)d_in[4];
  const float* b_gcn2 = (const float*)d_in[5];
  const float* wx[3]  = {(const float*)d_in[6],  (const float*)d_in[12], (const float*)d_in[18]};
  const float* bx[3]  = {(const float*)d_in[7],  (const float*)d_in[13], (const float*)d_in[19]};
  const float* bh[3]  = {(const float*)d_in[9],  (const float*)d_in[15], (const float*)d_in[21]};
  const float* wc[3]  = {(const float*)d_in[10], (const float*)d_in[16], (const float*)d_in[22]};
  const float* bg[3]  = {(const float*)d_in[11], (const float*)d_in[17], (const float*)d_in[23]};
  const float* lin_w  = (const float*)d_in[24];
  const float* lin_b  = (const float*)d_in[25];
  float* out = (float*)d_out;

  int N = in_sizes[0] / 16;
  int E = in_sizes[1] / 2;
  int nsb = (N + 255) / 256;

  char* ws = (char*)d_ws;
  size_t off = 0;
  auto alloc = [&](size_t bytes) {
    void* p = ws + off;
    off = (off + bytes + 255) & ~(size_t)255;
    return p;
  };
  int* deg      = (int*)alloc((size_t)N * 4);
  int* rowptr   = (int*)alloc((size_t)N * 4);
  int* cursor   = (int*)alloc((size_t)N * 4);
  int* bsum     = (int*)alloc((size_t)nsb * 4);
  int* csr_src  = (int*)alloc((size_t)E * 4);
  float* dinv_g = (float*)alloc((size_t)N * 4);
  float* dinv_c = (float*)alloc((size_t)N * 4);
  _Float16* Wpk = (_Float16*)alloc((size_t)3 * 36864 * 2);
  _Float16* bufA = (_Float16*)alloc((size_t)N * 64 * 2);
  _Float16* bufB = (_Float16*)alloc((size_t)N * 64 * 2);
  _Float16* bufC = (_Float16*)alloc((size_t)N * 64 * 2);
  (void)ws_size; (void)n_in; (void)out_size;

  const int tb = 256;
  hipMemsetAsync(deg, 0, (size_t)N * 4, stream);
  count_deg_kernel<<<(E + tb - 1) / tb, tb, 0, stream>>>(ei, deg, E);
  scan_block_sums<<<nsb, 256, 0, stream>>>(deg, bsum, N);
  scan_bsum<<<1, 256, 0, stream>>>(bsum, nsb);
  scan_final<<<nsb, 256, 0, stream>>>(deg, bsum, rowptr, cursor, dinv_g, dinv_c, N);
  fill_kernel<<<(E + tb - 1) / tb, tb, 0, stream>>>(ei, cursor, csr_src, E);
  pack_w_kernel<<<(110592 + 255) / 256, 256, 0, stream>>>(wx[0], wx[1], wx[2], Wpk);

  int nb16 = (N + 15) / 16;
  int nb64 = (N + 63) / 64;
  int nbw  = (N + 3) / 4;

  // GCN1 / GCN2 (tables fp16)
  rowmm16_kernel<<<nb16, 64, 0, stream>>>(x, w_gcn1, bufB, N);
  gather_kernel<0><<<nbw, 256, 0, stream>>>(rowptr, deg, csr_src, dinv_g, bufB, b_gcn1, bufA, N);
  rowmm64_kernel<<<nb16, 64, 0, stream>>>(bufA, w_gcn2, bufB, N);
  gather_kernel<0><<<nbw, 256, 0, stream>>>(rowptr, deg, csr_src, dinv_g, bufB, b_gcn2, bufA, N);

  // 3x GCLSTM: bufA = X -> H in place
  for (int l = 0; l < 3; ++l) {
    gather_kernel<1><<<nbw, 256, 0, stream>>>(rowptr, deg, csr_src, dinv_c, bufA, nullptr, bufB, N);
    gather_kernel<2><<<nbw, 256, 0, stream>>>(rowptr, deg, csr_src, dinv_c, bufB, bufA, bufC, N);
    gate_mfma_kernel<<<nb64, 256, 0, stream>>>(bufA, bufB, bufC, Wpk + (size_t)l * 36864,
                                               bx[l], bh[l], bg[l], wc[l], bufA, N);
  }

  linear_kernel<<<nbw, 256, 0, stream>>>(bufA, lin_w, lin_b, out, N);
}

// Round 5
// 398.077 us; speedup vs baseline: 2.8463x; 1.0700x over previous
//
#include <hip/hip_runtime.h>

// Social-STGCN forward: 2x GCN(improved) + 3x GCLSTM(K=3 Cheb, H=C=0) + linear.
// N=50000 nodes, E=800000 edges, D=64.
//
// Exact simplifications (H=C=0 per cell): gh(g)=bh[g]; f gate dead; Cn=i*t.
// Cheb terms z1=lhat(x), z2=2*lhat(z1)-x shared across gates.
// Aggregation commutes with feature matmul -> GCNs gather raw features first
// (GCN1 gathers 16-dim x: 32B rows, table L2-resident).
// Gate matmul [X|Z1|Z2](Nx192) @ W(192x192) on MFMA fp16; layer-3 gate fuses
// the final relu+linear (H3 never stored). csr_src stored as ushort (N<65536).

typedef _Float16 half8 __attribute__((ext_vector_type(8)));
typedef float f32x4 __attribute__((ext_vector_type(4)));

// ---------- CSR build ----------
__global__ void count_deg_kernel(const int* __restrict__ ei, int* __restrict__ deg, int E) {
  int e = blockIdx.x * blockDim.x + threadIdx.x;
  if (e < E) atomicAdd(&deg[ei[E + e]], 1);
}

__global__ void scan_block_sums(const int* __restrict__ deg, int* __restrict__ bsum, int n) {
  int tid = threadIdx.x;
  int i = blockIdx.x * 256 + tid;
  int v = (i < n) ? deg[i] : 0;
  for (int off = 32; off; off >>= 1) v += __shfl_down(v, off);
  __shared__ int ws[4];
  int lane = tid & 63, wid = tid >> 6;
  if (lane == 0) ws[wid] = v;
  __syncthreads();
  if (tid == 0) bsum[blockIdx.x] = ws[0] + ws[1] + ws[2] + ws[3];
}

// per-block exclusive scan of deg + block offset computed in-block from raw bsum;
// also fills cursor and both dinv arrays.
__global__ void scan_final(const int* __restrict__ deg, const int* __restrict__ bsum, int nb,
                           int* __restrict__ rowptr, int* __restrict__ cursor,
                           float* __restrict__ dg, float* __restrict__ dc, int n) {
  __shared__ int tmp[256];
  __shared__ int ws[4];
  __shared__ int base_sh;
  int tid = threadIdx.x;
  // block offset = sum of bsum[j] for j < blockIdx.x
  int v0 = (tid < nb && tid < (int)blockIdx.x) ? bsum[tid] : 0;
  for (int off = 32; off; off >>= 1) v0 += __shfl_down(v0, off);
  if ((tid & 63) == 0) ws[tid >> 6] = v0;
  __syncthreads();
  if (tid == 0) base_sh = ws[0] + ws[1] + ws[2] + ws[3];
  int i = blockIdx.x * 256 + tid;
  int v = (i < n) ? deg[i] : 0;
  tmp[tid] = v;
  __syncthreads();
  for (int off = 1; off < 256; off <<= 1) {
    int t = (tid >= off) ? tmp[tid - off] : 0;
    __syncthreads();
    tmp[tid] += t;
    __syncthreads();
  }
  if (i < n) {
    int excl = tmp[tid] - v + base_sh;
    rowptr[i] = excl;
    cursor[i] = excl;
    dg[i] = rsqrtf((float)v + 2.f);
    dc[i] = (v > 0) ? rsqrtf((float)v) : 0.f;
  }
}

__global__ void fill_kernel(const int* __restrict__ ei, int* __restrict__ cursor,
                            unsigned short* __restrict__ csr, int E) {
  int e = blockIdx.x * blockDim.x + threadIdx.x;
  if (e < E) {
    int d = ei[E + e];
    int pos = atomicAdd(&cursor[d], 1);
    csr[pos] = (unsigned short)ei[e];
  }
}

// ---------- cast x (N x 16 fp32) -> fp16 ----------
__global__ void cast_x16_kernel(const float* __restrict__ x, _Float16* __restrict__ x16, int total) {
  int i = blockIdx.x * blockDim.x + threadIdx.x;
  if (i < total) x16[i] = (_Float16)x[i];
}

// ---------- pack gate weights -> fp16 MFMA B-fragment layout ----------
// Wpk[l][g][kc][nt][lane][j]; g in {i,c,o} = src gates {0,2,3}; k = kc*32 + klo,
// klo = (lane>>4)*8 + j; n = nt*16 + (lane&15). Source wx: [4][3][64][64].
__global__ void pack_w_kernel(const float* __restrict__ wx0, const float* __restrict__ wx1,
                              const float* __restrict__ wx2, _Float16* __restrict__ Wpk) {
  int idx = blockIdx.x * 256 + threadIdx.x;
  if (idx >= 3 * 3 * 192 * 64) return;
  int l = idx / 36864;
  int r = idx % 36864;
  int g = r / 12288;
  int r2 = r % 12288;
  int k = r2 / 64;   // 0..191
  int n = r2 % 64;
  const float* wx = (l == 0) ? wx0 : (l == 1 ? wx1 : wx2);
  int gs = (g == 0) ? 0 : (g == 1 ? 2 : 3);
  int tau = k >> 6, kd = k & 63;
  float v = wx[(((size_t)gs * 3 + tau) * 64 + kd) * 64 + n];
  int kc = k >> 5, klo = k & 31;
  int lane = ((klo >> 3) << 4) | (n & 15);
  int j = klo & 7;
  int nt = n >> 4;
  size_t dst = ((((size_t)l * 3 + g) * 6 + kc) * 4 + nt) * 512 + (size_t)lane * 8 + j;
  Wpk[dst] = (_Float16)v;
}

// ---------- gather16: GCN raw agg on 16-dim fp16 rows; 2 nodes/wave ----------
// OUT[t] = dt*sum(dinv_s*X16_s) + 2*dt^2*X16_t   (bias/relu deferred to matmul)
__global__ void gather16_kernel(const int* __restrict__ rowptr, const int* __restrict__ deg,
                                const unsigned short* __restrict__ csr,
                                const float* __restrict__ dinv,
                                const _Float16* __restrict__ X16,
                                _Float16* __restrict__ OUT, int n) {
  int tid = threadIdx.x;
  int node = blockIdx.x * (blockDim.x >> 5) + (tid >> 5);
  if (node >= n) return;
  int l32 = tid & 31;
  int eg = l32 >> 1;   // 16 edge slots
  int c8 = l32 & 1;    // half8 chunk (8 feats)
  int beg = rowptr[node], end = beg + deg[node];
  const half8* IN8 = (const half8*)X16;  // 2 per row
  float acc[8];
#pragma unroll
  for (int j = 0; j < 8; ++j) acc[j] = 0.f;
  for (int p = beg + eg; p < end; p += 16) {
    int s = csr[p];
    float dv = dinv[s];
    half8 v = IN8[(size_t)s * 2 + c8];
#pragma unroll
    for (int j = 0; j < 8; ++j) acc[j] += dv * (float)v[j];
  }
#pragma unroll
  for (int j = 0; j < 8; ++j) {
    acc[j] += __shfl_xor(acc[j], 2);
    acc[j] += __shfl_xor(acc[j], 4);
    acc[j] += __shfl_xor(acc[j], 8);
    acc[j] += __shfl_xor(acc[j], 16);
  }
  if (eg == 0) {
    float dt = dinv[node];
    float c2 = 2.f * dt * dt;
    half8 self = IN8[(size_t)node * 2 + c8];
    half8 r;
#pragma unroll
    for (int j = 0; j < 8; ++j) r[j] = (_Float16)(dt * acc[j] + c2 * (float)self[j]);
    ((half8*)OUT)[(size_t)node * 2 + c8] = r;
  }
}

// ---------- gather (64-dim): one wave per node, 8 edge-slots x 8 half8-lanes ----------
// MODE 0: GCN raw -> OUT = dt*acc + 2*dt^2*IN[node]
// MODE 1: z1      -> OUT = -dt*acc
// MODE 2: z2      -> OUT = -2*dt*acc - AUX[node]  (AUX fp16 table)
template <int MODE>
__global__ void gather_kernel(const int* __restrict__ rowptr, const int* __restrict__ deg,
                              const unsigned short* __restrict__ csr,
                              const float* __restrict__ dinv,
                              const _Float16* __restrict__ IN, const _Float16* __restrict__ AUX,
                              _Float16* __restrict__ OUT, int n) {
  int node = blockIdx.x * (blockDim.x >> 6) + (threadIdx.x >> 6);
  if (node >= n) return;
  int lane = threadIdx.x & 63;
  int eg = lane >> 3;   // edge slot 0..7
  int c8 = lane & 7;    // half8 chunk of the 64-feature row
  int beg = rowptr[node], end = beg + deg[node];
  const half8* IN8 = (const half8*)IN;
  float acc[8];
#pragma unroll
  for (int j = 0; j < 8; ++j) acc[j] = 0.f;
  for (int p = beg + eg; p < end; p += 8) {
    int s = csr[p];
    float dv = dinv[s];
    half8 v = IN8[(size_t)s * 8 + c8];
#pragma unroll
    for (int j = 0; j < 8; ++j) acc[j] += dv * (float)v[j];
  }
#pragma unroll
  for (int j = 0; j < 8; ++j) {
    acc[j] += __shfl_xor(acc[j], 8);
    acc[j] += __shfl_xor(acc[j], 16);
    acc[j] += __shfl_xor(acc[j], 32);
  }
  if (eg == 0) {
    float dt = dinv[node];
    size_t o8 = (size_t)node * 8 + c8;
    half8 r;
    if (MODE == 0) {
      half8 self = IN8[o8];
      float c2 = 2.f * dt * dt;
#pragma unroll
      for (int j = 0; j < 8; ++j) r[j] = (_Float16)(dt * acc[j] + c2 * (float)self[j]);
    } else if (MODE == 1) {
#pragma unroll
      for (int j = 0; j < 8; ++j) r[j] = (_Float16)(-dt * acc[j]);
    } else {
      half8 xx = ((const half8*)AUX)[o8];
#pragma unroll
      for (int j = 0; j < 8; ++j) r[j] = (_Float16)(-2.f * dt * acc[j] - (float)xx[j]);
    }
    ((half8*)OUT)[o8] = r;
  }
}

// ---------- GCN1: h1 = relu(A16[n][16] @ W[16][64] + b)  (fp16 in/out) ----------
__global__ __launch_bounds__(64) void rowmm16f_kernel(const _Float16* __restrict__ A,
                                                      const float* __restrict__ W,
                                                      const float* __restrict__ bias,
                                                      _Float16* __restrict__ OUT, int n) {
  __shared__ float xt[256];
  int tid = threadIdx.x;
  int n0 = blockIdx.x * 16;
  for (int idx = tid; idx < 256; idx += 64) {
    int row = idx >> 4, col = idx & 15;
    int gr = min(n0 + row, n - 1);
    xt[idx] = (float)A[(size_t)gr * 16 + col];
  }
  __syncthreads();
  float acc[16];
  float b = bias[tid];
#pragma unroll
  for (int t = 0; t < 16; ++t) acc[t] = b;
  for (int k = 0; k < 16; ++k) {
    float w = W[k * 64 + tid];
#pragma unroll
    for (int t = 0; t < 16; ++t) acc[t] += xt[t * 16 + k] * w;
  }
#pragma unroll
  for (int t = 0; t < 16; ++t) {
    int node = n0 + t;
    if (node < n) OUT[(size_t)node * 64 + tid] = (_Float16)fmaxf(acc[t], 0.f);
  }
}

// ---------- GCN2: h2 = relu(A[n][64] @ W[64][64] + b)  (fp16 in/out) ----------
__global__ __launch_bounds__(64) void rowmm64f_kernel(const _Float16* __restrict__ A,
                                                      const float* __restrict__ W,
                                                      const float* __restrict__ bias,
                                                      _Float16* __restrict__ OUT, int n) {
  __shared__ float xt[16 * 64];
  int tid = threadIdx.x;
  int n0 = blockIdx.x * 16;
  const half8* A8 = (const half8*)A;
#pragma unroll
  for (int it = 0; it < 2; ++it) {
    int i8 = it * 64 + tid;             // 0..127 (16 rows x 8 chunks)
    int row = i8 >> 3, c8 = i8 & 7;
    int gr = min(n0 + row, n - 1);
    half8 v = A8[(size_t)gr * 8 + c8];
#pragma unroll
    for (int j = 0; j < 8; ++j) xt[row * 64 + c8 * 8 + j] = (float)v[j];
  }
  __syncthreads();
  float acc[16];
  float b = bias[tid];
#pragma unroll
  for (int t = 0; t < 16; ++t) acc[t] = b;
  for (int k = 0; k < 64; ++k) {
    float w = W[k * 64 + tid];
#pragma unroll
    for (int t = 0; t < 16; ++t) acc[t] += xt[t * 64 + k] * w;
  }
#pragma unroll
  for (int t = 0; t < 16; ++t) {
    int node = n0 + t;
    if (node < n) OUT[(size_t)node * 64 + tid] = (_Float16)fmaxf(acc[t], 0.f);
  }
}

// ---------- MFMA gate kernel: 64 nodes/block, 16 nodes/wave, no LDS ----------
// A frag direct from fp16 tables: row m=lane&15, k=(lane>>4)*8+j.
// D: col n=lane&15, row m=(lane>>4)*4+r.
// FINAL=1: fuse out = relu(H) @ lin_w + lin_b (H never stored).
template <int FINAL>
__global__ __launch_bounds__(256) void gate_mfma_kernel(
    const _Float16* __restrict__ X, const _Float16* __restrict__ Z1,
    const _Float16* __restrict__ Z2,
    const _Float16* __restrict__ Wl,  // packed [3][6][4][64][8] for this layer
    const float* __restrict__ bx, const float* __restrict__ bh, const float* __restrict__ bg,
    const float* __restrict__ wc, _Float16* __restrict__ H,
    const float* __restrict__ lw, const float* __restrict__ lb,
    float* __restrict__ out, int n) {
  int tid = threadIdx.x;
  int wid = tid >> 6, lane = tid & 63;
  int n0 = blockIdx.x * 64;
  int row = n0 + wid * 16 + (lane & 15);
  int rowc = min(row, n - 1);               // clamped load row (stores guarded)
  int ksub = (lane >> 4) << 3;              // 0,8,16,24
  const _Float16* Wlane = Wl + (size_t)lane * 8;
  int dbase = lane & 15;

  f32x4 acc[3][4];
#pragma unroll
  for (int g = 0; g < 3; ++g) {
    int gs = (g == 0) ? 0 : (g == 1 ? 2 : 3);
#pragma unroll
    for (int nt = 0; nt < 4; ++nt) {
      int d = nt * 16 + dbase;
      float b = bx[gs * 64 + d] + bh[gs * 64 + d] + bg[gs * 64 + d];
      acc[g][nt] = (f32x4){b, b, b, b};
    }
  }
  const _Float16* T[3] = {X, Z1, Z2};
#pragma unroll
  for (int kc = 0; kc < 6; ++kc) {
    const _Float16* t = T[kc >> 1];
    half8 a = *(const half8*)&t[(size_t)rowc * 64 + ((kc & 1) << 5) + ksub];
#pragma unroll
    for (int g = 0; g < 3; ++g) {
#pragma unroll
      for (int nt = 0; nt < 4; ++nt) {
        half8 b = *(const half8*)(Wlane + (size_t)((g * 6 + kc) * 4 + nt) * 512);
        acc[g][nt] = __builtin_amdgcn_mfma_f32_16x16x32_f16(a, b, acc[g][nt], 0, 0, 0);
      }
    }
  }
  int mrow = n0 + wid * 16 + ((lane >> 4) << 2);
  float po[4][3];
  if (FINAL) {
#pragma unroll
    for (int r = 0; r < 4; ++r) { po[r][0] = 0.f; po[r][1] = 0.f; po[r][2] = 0.f; }
  }
#pragma unroll
  for (int nt = 0; nt < 4; ++nt) {
    int d = nt * 16 + dbase;
    float wcd = wc[128 + d];
#pragma unroll
    for (int r = 0; r < 4; ++r) {
      float ig = 1.f / (1.f + expf(-acc[0][nt][r]));
      float tt = tanhf(acc[1][nt][r]);
      float Cn = ig * tt;
      float og = 1.f / (1.f + expf(-(acc[2][nt][r] + wcd * Cn)));
      float h = og * tanhf(Cn);
      if (FINAL) {
        float rl = fmaxf(h, 0.f);
        po[r][0] += rl * lw[d * 3 + 0];
        po[r][1] += rl * lw[d * 3 + 1];
        po[r][2] += rl * lw[d * 3 + 2];
      } else {
        int node = mrow + r;
        if (node < n) H[(size_t)node * 64 + d] = (_Float16)h;
      }
    }
  }
  if (FINAL) {
    // reduce across the 16 feature-lanes (lane bits 0..3)
#pragma unroll
    for (int m = 1; m < 16; m <<= 1) {
#pragma unroll
      for (int r = 0; r < 4; ++r) {
        po[r][0] += __shfl_xor(po[r][0], m);
        po[r][1] += __shfl_xor(po[r][1], m);
        po[r][2] += __shfl_xor(po[r][2], m);
      }
    }
    if (dbase == 0) {
#pragma unroll
      for (int r = 0; r < 4; ++r) {
        int node = mrow + r;
        if (node < n) {
          out[(size_t)node * 3 + 0] = po[r][0] + lb[0];
          out[(size_t)node * 3 + 1] = po[r][1] + lb[1];
          out[(size_t)node * 3 + 2] = po[r][2] + lb[2];
        }
      }
    }
  }
}

extern "C" void kernel_launch(void* const* d_in, const int* in_sizes, int n_in,
                              void* d_out, int out_size, void* d_ws, size_t ws_size,
                              hipStream_t stream) {
  const float* x      = (const float*)d_in[0];
  const int*   ei     = (const int*)d_in[1];
  const float* w_gcn1 = (const float*)d_in[2];
  const float* b_gcn1 = (const float*)d_in[3];
  const float* w_gcn2 = (const float*)d_in[4];
  const float* b_gcn2 = (const float*)d_in[5];
  const float* wx[3]  = {(const float*)d_in[6],  (const float*)d_in[12], (const float*)d_in[18]};
  const float* bx[3]  = {(const float*)d_in[7],  (const float*)d_in[13], (const float*)d_in[19]};
  const float* bh[3]  = {(const float*)d_in[9],  (const float*)d_in[15], (const float*)d_in[21]};
  const float* wc[3]  = {(const float*)d_in[10], (const float*)d_in[16], (const float*)d_in[22]};
  const float* bg[3]  = {(const float*)d_in[11], (const float*)d_in[17], (const float*)d_in[23]};
  const float* lin_w  = (const float*)d_in[24];
  const float* lin_b  = (const float*)d_in[25];
  float* out = (float*)d_out;

  int N = in_sizes[0] / 16;
  int E = in_sizes[1] / 2;
  int nsb = (N + 255) / 256;

  char* ws = (char*)d_ws;
  size_t off = 0;
  auto alloc = [&](size_t bytes) {
    void* p = ws + off;
    off = (off + bytes + 255) & ~(size_t)255;
    return p;
  };
  int* deg        = (int*)alloc((size_t)N * 4);
  int* rowptr     = (int*)alloc((size_t)N * 4);
  int* cursor     = (int*)alloc((size_t)N * 4);
  int* bsum       = (int*)alloc((size_t)nsb * 4);
  unsigned short* csr = (unsigned short*)alloc((size_t)E * 2);
  float* dinv_g   = (float*)alloc((size_t)N * 4);
  float* dinv_c   = (float*)alloc((size_t)N * 4);
  _Float16* Wpk   = (_Float16*)alloc((size_t)3 * 36864 * 2);
  _Float16* x16   = (_Float16*)alloc((size_t)N * 16 * 2);
  _Float16* a16   = (_Float16*)alloc((size_t)N * 16 * 2);
  _Float16* bufA  = (_Float16*)alloc((size_t)N * 64 * 2);
  _Float16* bufB  = (_Float16*)alloc((size_t)N * 64 * 2);
  _Float16* bufC  = (_Float16*)alloc((size_t)N * 64 * 2);
  (void)ws_size; (void)n_in; (void)out_size;

  const int tb = 256;
  hipMemsetAsync(deg, 0, (size_t)N * 4, stream);
  count_deg_kernel<<<(E + tb - 1) / tb, tb, 0, stream>>>(ei, deg, E);
  scan_block_sums<<<nsb, 256, 0, stream>>>(deg, bsum, N);
  scan_final<<<nsb, 256, 0, stream>>>(deg, bsum, nsb, rowptr, cursor, dinv_g, dinv_c, N);
  fill_kernel<<<(E + tb - 1) / tb, tb, 0, stream>>>(ei, cursor, csr, E);
  pack_w_kernel<<<(110592 + 255) / 256, 256, 0, stream>>>(wx[0], wx[1], wx[2], Wpk);
  cast_x16_kernel<<<(N * 16 + 255) / 256, 256, 0, stream>>>(x, x16, N * 16);

  int nb16 = (N + 15) / 16;
  int nb64 = (N + 63) / 64;
  int nbw  = (N + 3) / 4;   // 4 node-waves per 256-thread block (64-dim gathers)
  int nbw2 = (N + 7) / 8;   // 8 node-halfwaves per block (16-dim gather)

  // GCN1: agg16 = raw agg of x16; h1 = relu(agg16 @ W1 + b1)
  gather16_kernel<<<nbw2, 256, 0, stream>>>(rowptr, deg, csr, dinv_g, x16, a16, N);
  rowmm16f_kernel<<<nb16, 64, 0, stream>>>(a16, w_gcn1, b_gcn1, bufA, N);
  // GCN2: aggB = raw agg of h1; h2 = relu(aggB @ W2 + b2)
  gather_kernel<0><<<nbw, 256, 0, stream>>>(rowptr, deg, csr, dinv_g, bufA, nullptr, bufB, N);
  rowmm64f_kernel<<<nb16, 64, 0, stream>>>(bufB, w_gcn2, b_gcn2, bufA, N);

  // 3x GCLSTM: bufA = X -> H in place; layer 3 fuses the final linear
  for (int l = 0; l < 3; ++l) {
    gather_kernel<1><<<nbw, 256, 0, stream>>>(rowptr, deg, csr, dinv_c, bufA, nullptr, bufB, N);
    gather_kernel<2><<<nbw, 256, 0, stream>>>(rowptr, deg, csr, dinv_c, bufB, bufA, bufC, N);
    if (l < 2) {
      gate_mfma_kernel<0><<<nb64, 256, 0, stream>>>(bufA, bufB, bufC, Wpk + (size_t)l * 36864,
                                                    bx[l], bh[l], bg[l], wc[l], bufA,
                                                    nullptr, nullptr, nullptr, N);
    } else {
      gate_mfma_kernel<1><<<nb64, 256, 0, stream>>>(bufA, bufB, bufC, Wpk + (size_t)l * 36864,
                                                    bx[l], bh[l], bg[l], wc[l], nullptr,
                                                    lin_w, lin_b, out, N);
    }
  }
}